// Round 6
// baseline (467.017 us; speedup 1.0000x reference)
//
#include <hip/hip_runtime.h>
#include <hip/hip_bf16.h>
#include <math.h>

// Problem: B=32, L=2048, E=512, Q=512, K=E+Q=1024, M=B*L=65536
// out = [applied (32*512 f32), weights (32*2048 f32)]
//
// r5 lessons: (a) pre-converted bf16 GEMM hits the m97 plateau (~85us) but the
// convert pass (130us @ 2TB/s) cancels the win; (b) r2's fused kernel is
// latency-bound: a full HBM load latency sits inside every 2-barrier K-iter.
// r6: producer-consumer wave specialization. 512-thr blocks; waves 0-3 MFMA,
// waves 4-7 load fp32 + cvt->bf16 into double-buffered LDS, register-
// pipelining one tile ahead (plain VGPR-dest loads survive s_barrier; only
// LDS-visible ops need draining).

typedef __attribute__((ext_vector_type(8))) short bf16x8;
typedef __attribute__((ext_vector_type(4))) float f32x4;
typedef unsigned short u16;

#define BDIM 32
#define LDIM 2048
#define EDIM 512
#define QDIM 512
#define KDIM 1024
#define MDIM (BDIM * LDIM)
#define NTILES 16                 // KDIM / 64
#define LDS_STRIDE 72             // 144B rows (r2-proven)

// exact RNE pack: v_cvt_pk_bf16_f32 (1 inst / 2 elems)
__device__ inline unsigned int pack2(float lo, float hi) {
    __hip_bfloat162 h = __float22bfloat162_rn(float2{lo, hi});
    unsigned int u;
    __builtin_memcpy(&u, &h, sizeof(u));
    return u;
}

// tanh via hw v_exp_f32: 1 - 2/(e^{2x}+1)
__device__ inline float fast_tanh(float x) {
    float e = __expf(2.0f * x);
    return 1.0f - 2.0f / (e + 1.0f);
}

__global__ __launch_bounds__(512) void scores_pc_kernel(
    const float* __restrict__ emb, const float* __restrict__ query,
    const float* __restrict__ W, const float* __restrict__ b_attn,
    const float* __restrict__ v_w, float* __restrict__ scores)
{
    __shared__ u16 As[2][128][LDS_STRIDE];
    __shared__ u16 Bs[2][128][LDS_STRIDE];

    const int tid = threadIdx.x;
    const int bid = blockIdx.x;
    // XCD-aware swizzle (r2: FETCH 545->164MB)
    const int xcd = bid & 7;
    const int slot = bid >> 3;
    const int mtile = xcd * 64 + (slot >> 2);
    const int ntile = slot & 3;
    const int m0 = mtile * 128;
    const int n0 = ntile * 128;

    const int wv = tid >> 6;              // 0..7
    const bool producer = wv >= 4;

    // ---------------- producer lane constants ----------------
    const int ptid = tid & 255;           // 0..255 for waves 4-7
    const int row16 = ptid >> 4;          // 0..15
    const int col4 = (ptid & 15) * 4;     // 0..60

    // ---------------- consumer lane constants ----------------
    const int lane = tid & 63;
    const int cwm = ((wv & 3) >> 1) * 64;
    const int cwn = (wv & 1) * 64;
    const int quad = lane >> 4;
    const int ln = lane & 15;

    float4 pa[8], pb[8];

    // ---------------- prologue: producers stage tile 0, issue tile 1 ----------------
    if (producer) {
        #pragma unroll
        for (int p = 0; p < 8; p++)
            pa[p] = *(const float4*)(query + (size_t)(m0 + p * 16 + row16) * 512 + col4);
        #pragma unroll
        for (int p = 0; p < 8; p++)
            pb[p] = *(const float4*)(W + (size_t)(n0 + p * 16 + row16) * 1024 + col4);
        #pragma unroll
        for (int p = 0; p < 8; p++) {
            uint2 pk;
            pk.x = pack2(pa[p].x, pa[p].y);
            pk.y = pack2(pa[p].z, pa[p].w);
            *(uint2*)&As[0][p * 16 + row16][col4] = pk;
        }
        #pragma unroll
        for (int p = 0; p < 8; p++) {
            uint2 pk;
            pk.x = pack2(pb[p].x, pb[p].y);
            pk.y = pack2(pb[p].z, pb[p].w);
            *(uint2*)&Bs[0][p * 16 + row16][col4] = pk;
        }
        // issue tile 1 loads (in flight across the barrier)
        #pragma unroll
        for (int p = 0; p < 8; p++)
            pa[p] = *(const float4*)(query + (size_t)(m0 + p * 16 + row16) * 512 + 64 + col4);
        #pragma unroll
        for (int p = 0; p < 8; p++)
            pb[p] = *(const float4*)(W + (size_t)(n0 + p * 16 + row16) * 1024 + 64 + col4);
    }

    f32x4 acc[4][4];
    #pragma unroll
    for (int i = 0; i < 4; i++)
        #pragma unroll
        for (int j = 0; j < 4; j++)
            acc[i][j] = (f32x4){0.f, 0.f, 0.f, 0.f};

    __syncthreads();   // buf0 ready

    #pragma unroll 2
    for (int k = 0; k < NTILES; k++) {
        if (producer) {
            const int t = k + 1;              // tile to convert+write this iter
            if (t < NTILES) {
                const int kb = t & 1;
                #pragma unroll
                for (int p = 0; p < 8; p++) {
                    uint2 pk;
                    pk.x = pack2(pa[p].x, pa[p].y);
                    pk.y = pack2(pa[p].z, pa[p].w);
                    *(uint2*)&As[kb][p * 16 + row16][col4] = pk;
                }
                #pragma unroll
                for (int p = 0; p < 8; p++) {
                    uint2 pk;
                    pk.x = pack2(pb[p].x, pb[p].y);
                    pk.y = pack2(pb[p].z, pb[p].w);
                    *(uint2*)&Bs[kb][p * 16 + row16][col4] = pk;
                }
                const int t2 = t + 1;         // tile to issue loads for
                if (t2 < NTILES) {
                    const float* asrc = (t2 < 8) ? query : emb;
                    const int koff = (t2 * 64) & (QDIM - 1);
                    #pragma unroll
                    for (int p = 0; p < 8; p++)
                        pa[p] = *(const float4*)(asrc + (size_t)(m0 + p * 16 + row16) * 512 + koff + col4);
                    #pragma unroll
                    for (int p = 0; p < 8; p++)
                        pb[p] = *(const float4*)(W + (size_t)(n0 + p * 16 + row16) * 1024 + t2 * 64 + col4);
                }
            }
        } else {
            const int kb = k & 1;
            #pragma unroll
            for (int ks = 0; ks < 2; ks++) {
                bf16x8 af[4], bfr[4];
                #pragma unroll
                for (int i = 0; i < 4; i++)
                    af[i] = *(const bf16x8*)&As[kb][cwm + i * 16 + ln][ks * 32 + quad * 8];
                #pragma unroll
                for (int j = 0; j < 4; j++)
                    bfr[j] = *(const bf16x8*)&Bs[kb][cwn + j * 16 + ln][ks * 32 + quad * 8];
                #pragma unroll
                for (int i = 0; i < 4; i++)
                    #pragma unroll
                    for (int j = 0; j < 4; j++)
                        acc[i][j] = __builtin_amdgcn_mfma_f32_16x16x32_bf16(af[i], bfr[j], acc[i][j], 0, 0, 0);
            }
        }
        __syncthreads();
    }

    // ---------------- epilogue (consumer waves only; no barriers) ----------------
    if (!producer) {
        float bj[4], vj[4];
        #pragma unroll
        for (int j = 0; j < 4; j++) {
            const int n = n0 + cwn + j * 16 + ln;
            bj[j] = b_attn[n];
            vj[j] = v_w[n];
        }
        #pragma unroll
        for (int i = 0; i < 4; i++) {
            #pragma unroll
            for (int r = 0; r < 4; r++) {
                float s = 0.f;
                #pragma unroll
                for (int j = 0; j < 4; j++)
                    s += fast_tanh(acc[i][j][r] + bj[j]) * vj[j];
                #pragma unroll
                for (int off = 1; off < 16; off <<= 1)
                    s += __shfl_xor(s, off, 64);
                if (ln == 0)
                    atomicAdd(&scores[m0 + cwm + i * 16 + quad * 4 + r], s);
            }
        }
    }
}

__global__ __launch_bounds__(256) void softmax_apply_kernel(
    const float* __restrict__ emb, const float* __restrict__ scores,
    float* __restrict__ out_applied, float* __restrict__ out_weights)
{
    const int b = blockIdx.x >> 5;      // 32 L-chunks of 64 rows
    const int chunk = blockIdx.x & 31;
    const int l0 = chunk * 64;
    const int tid = threadIdx.x;
    const float* srow = scores + b * LDIM;

    __shared__ float red[4];
    __shared__ float wls[64];
    __shared__ float partial[128 * 4];

    float mx = -1e30f;
    #pragma unroll
    for (int t = 0; t < 8; t++) mx = fmaxf(mx, srow[tid + t * 256]);
    #pragma unroll
    for (int off = 1; off < 64; off <<= 1) mx = fmaxf(mx, __shfl_xor(mx, off, 64));
    if ((tid & 63) == 0) red[tid >> 6] = mx;
    __syncthreads();
    mx = fmaxf(fmaxf(red[0], red[1]), fmaxf(red[2], red[3]));

    float sm = 0.f;
    #pragma unroll
    for (int t = 0; t < 8; t++) sm += expf(srow[tid + t * 256] - mx);
    #pragma unroll
    for (int off = 1; off < 64; off <<= 1) sm += __shfl_xor(sm, off, 64);
    __syncthreads();
    if ((tid & 63) == 0) red[tid >> 6] = sm;
    __syncthreads();
    sm = red[0] + red[1] + red[2] + red[3];
    const float inv = 1.f / sm;

    if (tid < 64) {
        const float w = expf(srow[l0 + tid] - mx) * inv;
        wls[tid] = w;
        out_weights[(size_t)b * LDIM + l0 + tid] = w;
    }
    __syncthreads();

    const int half = tid >> 7;
    const int cg = tid & 127;
    float4 acc = {0.f, 0.f, 0.f, 0.f};
    const float* ebase = emb + ((size_t)b * LDIM + l0 + half) * EDIM + cg * 4;
    #pragma unroll 8
    for (int i = 0; i < 32; i++) {
        const float4 v = *(const float4*)(ebase + (size_t)2 * i * EDIM);
        const float w = wls[half + 2 * i];
        acc.x += w * v.x;
        acc.y += w * v.y;
        acc.z += w * v.z;
        acc.w += w * v.w;
    }
    if (half == 1) *(float4*)&partial[cg * 4] = acc;
    __syncthreads();
    if (half == 0) {
        const float4 p = *(const float4*)&partial[cg * 4];
        float* dst = out_applied + b * EDIM + cg * 4;
        atomicAdd(dst + 0, acc.x + p.x);
        atomicAdd(dst + 1, acc.y + p.y);
        atomicAdd(dst + 2, acc.z + p.z);
        atomicAdd(dst + 3, acc.w + p.w);
    }
}

extern "C" void kernel_launch(void* const* d_in, const int* in_sizes, int n_in,
                              void* d_out, int out_size, void* d_ws, size_t ws_size,
                              hipStream_t stream) {
    const float* emb    = (const float*)d_in[0];
    const float* query  = (const float*)d_in[1];
    const float* W      = (const float*)d_in[2];
    const float* b_attn = (const float*)d_in[3];
    const float* v_w    = (const float*)d_in[4];

    float* out     = (float*)d_out;
    float* applied = out;                 // 32*512 floats
    float* weights = out + BDIM * EDIM;   // 32*2048 floats
    float* scores  = (float*)d_ws;        // 65536 floats = 256 KB scratch

    (void)hipMemsetAsync(scores, 0, (size_t)MDIM * sizeof(float), stream);
    (void)hipMemsetAsync(applied, 0, (size_t)BDIM * EDIM * sizeof(float), stream);

    // grid = (M/128) * (N/128) = 512 * 4 = 2048 blocks, 512 threads each
    scores_pc_kernel<<<2048, 512, 0, stream>>>(emb, query, W, b_attn, v_w, scores);

    // grid = B * 32 chunks = 1024 blocks
    softmax_apply_kernel<<<1024, 256, 0, stream>>>(emb, scores, applied, weights);
}